// Round 13
// baseline (1269.133 us; speedup 1.0000x reference)
//
#include <hip/hip_runtime.h>
#include <stdint.h>

#define N_SEQ 16384
#define T_LEN 16
#define E_DIM 256
#define H_DIM 256
#define B_SAMP 128
#define V_SIZE 10000

typedef __bf16 bf16x8 __attribute__((ext_vector_type(8)));
typedef float  f32x4  __attribute__((ext_vector_type(4)));
typedef unsigned short ush;

__device__ __forceinline__ ush f2bf(float x) {
  unsigned int u = __float_as_uint(x);
  u = (u + 0x7fffu + ((u >> 16) & 1u)) >> 16;
  return (ush)u;
}
__device__ __forceinline__ float bf2f(ush v) {
  return __uint_as_float(((unsigned int)v) << 16);
}
__device__ __forceinline__ float sigmoidf_(float x) {
  return 1.0f / (1.0f + __expf(-x));
}
__device__ __forceinline__ float tanhf_(float x) {
  float e = __expf(2.0f * x);
  return 1.0f - 2.0f / (e + 1.0f);
}
__device__ __forceinline__ void glds16(const void* g, const void* l) {
  __builtin_amdgcn_global_load_lds(
      (const __attribute__((address_space(1))) unsigned int*)g,
      (__attribute__((address_space(3))) unsigned int*)l, 16, 0, 0);
}

// ---------------- prep kernels ----------------

__global__ __launch_bounds__(256) void k_lens(const int* __restrict__ tok, int* __restrict__ lens,
                                              int* __restrict__ hist) {
  __shared__ int lh[17];
  if (threadIdx.x < 17) lh[threadIdx.x] = 0;
  __syncthreads();
  int n = blockIdx.x * 256 + threadIdx.x;
  const int* r = tok + n * T_LEN;
  int c = 0;
#pragma unroll
  for (int t = 0; t < T_LEN; ++t) c += (r[t] != 0);
  lens[n] = c;
  atomicAdd(&lh[c], 1);
  __syncthreads();
  if (threadIdx.x < 17 && lh[threadIdx.x]) atomicAdd(&hist[threadIdx.x], lh[threadIdx.x]);
}

// descending-length bucket starts; cnts[t] = count(len > t) — active prefix for BOTH dirs
// (parity pooling removes the need for graduation copies entirely)
__global__ void k_offsets(const int* __restrict__ hist, int* __restrict__ cursor,
                          int* __restrict__ cnts) {
  if (threadIdx.x == 0) {
    int off = 0;
    for (int l = 16; l >= 0; --l) { cursor[l] = off; off += hist[l]; }
    for (int t = 0; t < 16; ++t) {
      int c = 0;
      for (int l = t + 1; l <= 16; ++l) c += hist[l];
      cnts[t] = c;
    }
  }
}

__global__ __launch_bounds__(256) void k_scatter(const int* __restrict__ lens, int* __restrict__ cursor,
                                                 int* __restrict__ perm, int* __restrict__ pinv,
                                                 int* __restrict__ plens) {
  int n = blockIdx.x * 256 + threadIdx.x;
  int l = lens[n];
  int pos = atomicAdd(&cursor[l], 1);
  perm[pos] = n;
  pinv[n] = pos;
  plens[pos] = l;
}

// gather form: coalesced writes, tok (1 MB) is L2-resident
__global__ __launch_bounds__(256) void k_tokperm(const int* __restrict__ tok, const int* __restrict__ perm,
                                                 int* __restrict__ tokperm) {
  int id = blockIdx.x * 256 + threadIdx.x;  // < T_LEN * N_SEQ
  int t = id >> 14;                          // N_SEQ = 2^14
  int pos = id & (N_SEQ - 1);
  tokperm[id] = tok[perm[pos] * T_LEN + t];
}

__global__ __launch_bounds__(256) void k_embcvt(const float* __restrict__ emb, ush* __restrict__ out) {
  int i = blockIdx.x * 256 + threadIdx.x;
  out[i] = f2bf(emb[i]);
}

// Permuted weights: p = nb*256 + wc*64 + q*16 + jj  <->  j = nb*64 + wc*16 + jj,
// gate-row r = q*256 + j. mat0: Wih -> wihp[dir][p][k] (K=256); mat1: Whh -> whhp[dir][p][k].
__global__ __launch_bounds__(256) void k_wprep(const float* __restrict__ Wih_f, const float* __restrict__ Whh_f,
                                               const float* __restrict__ Wih_b, const float* __restrict__ Whh_b,
                                               ush* __restrict__ wihp_f, ush* __restrict__ wihp_b,
                                               ush* __restrict__ whhp_f, ush* __restrict__ whhp_b) {
  int id = blockIdx.x * 256 + threadIdx.x;  // < 2*2*1024*256
  int mat = id >> 19;
  int dir = (id >> 18) & 1;
  int rem = id & ((1 << 18) - 1);
  int p = rem >> 8;
  int k = rem & 255;
  int nb = p >> 8, wc = (p >> 6) & 3, q = (p >> 4) & 3, jj = p & 15;
  int r = q * 256 + nb * 64 + wc * 16 + jj;
  const float* src = mat ? (dir ? Whh_b : Whh_f) : (dir ? Wih_b : Wih_f);
  ush* dst = mat ? (dir ? whhp_b : whhp_f) : (dir ? wihp_b : wihp_f);
  dst[p * 256 + k] = f2bf(src[r * 256 + k]);
}

// ---------------- vocab projection: proj[v][j*4+q] = emb[v]·W_ih[q,j] + bias[q,j], f32 ----------------
// R5-proven geometry: 512 thr / 8 waves (2x4), tile 128 v-rows x 256 pcols, K=256 in 4 chunks,
// single-buffer 48KB LDS, XOR swizzle.

__global__ __launch_bounds__(512, 4)
void k_vproj(const ush* __restrict__ embbf,
             const ush* __restrict__ wihp_f, const ush* __restrict__ wihp_b,
             const float* __restrict__ bias_f, const float* __restrict__ bias_b,
             float* __restrict__ proj_f, float* __restrict__ proj_b) {
  const int dir = blockIdx.y;
  const int vt = blockIdx.x >> 2;
  const int nblk = blockIdx.x & 3;
  const int m0 = vt * 128;
  const ush* wih = dir ? wihp_b : wihp_f;
  const float* bias = dir ? bias_b : bias_f;
  float* proj = dir ? proj_b : proj_f;

  __shared__ __align__(128) unsigned char ldsA[128 * 128];
  __shared__ __align__(128) unsigned char ldsB[256 * 128];

  const int tid = threadIdx.x;
  const int lane = tid & 63;
  const int w = tid >> 6;
  const int wr = w >> 2, wc = w & 3;
  const int l8 = lane >> 3, l7 = lane & 7;
  const int frow = lane & 15, fkq = lane >> 4;

  const int arow0 = 16 * w + l8, arow1 = arow0 + 8;
  const unsigned aoff0 = (unsigned)(m0 + arow0) * 256 + (l7 ^ (arow0 & 7)) * 8;
  const unsigned aoff1 = (unsigned)(m0 + arow1) * 256 + (l7 ^ (arow1 & 7)) * 8;
  unsigned boff[4];
#pragma unroll
  for (int jj = 0; jj < 4; ++jj) {
    const int brow = 32 * w + 8 * jj + l8;
    boff[jj] = (unsigned)(nblk * 256 + brow) * 256 + (l7 ^ (brow & 7)) * 8;
  }

  f32x4 acc[4][4] = {};
  for (int kt = 0; kt < 4; ++kt) {
    const int k0 = kt * 64;
    glds16(embbf + aoff0 + k0, &ldsA[(16 * w) * 128]);
    glds16(embbf + aoff1 + k0, &ldsA[(16 * w + 8) * 128]);
#pragma unroll
    for (int jj = 0; jj < 4; ++jj)
      glds16(wih + boff[jj] + k0, &ldsB[(32 * w + 8 * jj) * 128]);
    __syncthreads();
#pragma unroll
    for (int ksub = 0; ksub < 2; ++ksub) {
      bf16x8 av[4], bv[4];
#pragma unroll
      for (int fr = 0; fr < 4; ++fr) {
        const int row = wr * 64 + fr * 16 + frow;
        av[fr] = *(const bf16x8*)&ldsA[row * 128 + (((ksub * 4 + fkq) ^ (row & 7)) * 16)];
      }
#pragma unroll
      for (int fc = 0; fc < 4; ++fc) {
        const int row = wc * 64 + fc * 16 + frow;
        bv[fc] = *(const bf16x8*)&ldsB[row * 128 + (((ksub * 4 + fkq) ^ (row & 7)) * 16)];
      }
#pragma unroll
      for (int fr = 0; fr < 4; ++fr)
#pragma unroll
        for (int fc = 0; fc < 4; ++fc)
          acc[fr][fc] = __builtin_amdgcn_mfma_f32_16x16x32_bf16(av[fr], bv[fc], acc[fr][fc], 0, 0, 0);
    }
    __syncthreads();
  }

  // write proj[v][j*4+q] with bias folded; fc == gate q, j = nblk*64 + wc*16 + frow
  const int j = nblk * 64 + wc * 16 + frow;
  const f32x4 pb = {bias[j], bias[256 + j], bias[512 + j], bias[768 + j]};
#pragma unroll
  for (int fr = 0; fr < 4; ++fr) {
    const int v0 = m0 + wr * 64 + fr * 16 + fkq * 4;
#pragma unroll
    for (int r = 0; r < 4; ++r) {
      if (v0 + r < V_SIZE) {
        f32x4 v4 = {acc[fr][0][r], acc[fr][1][r], acc[fr][2][r], acc[fr][3][r]};
        *(f32x4*)&proj[(size_t)(v0 + r) * 1024 + j * 4] = v4 + pb;
      }
    }
  }
}

// ---------------- LSTM step: K=256 recurrent GEMM + proj epilogue + fused cell ----------------
// R5-proven core: 512 thr / 8 waves (2x4), tile 128 rows x 256 pcols, K=256 in 4 chunks of 64,
// single-buffer 48KB LDS, XOR swizzle (conflict-free, measured). R8 XCD decode:
// b&1=dir, (b&7)>>1=nblk, b>>3=rt -> each XCD owns one (dir,nblk) B-slice (L2-resident).
// Parity pooling: NO graduation copies; rows past prefix (len<=t) are never touched.
// c f32 in cT[j][n] (full 64B lines), prefetched with lens/tokens before the GEMM.

__global__ __launch_bounds__(512, 4)
void k_step(const float* __restrict__ proj_f, const float* __restrict__ proj_b,
            const int* __restrict__ tokperm, const int* __restrict__ plens,
            const int* __restrict__ cnts,
            const ush* __restrict__ whhp_f, const ush* __restrict__ whhp_b,
            const ush* __restrict__ hr_f, ush* __restrict__ hw_f,
            const ush* __restrict__ hr_b, ush* __restrict__ hw_b,
            float* __restrict__ cT_f, float* __restrict__ cT_b,
            int s) {
  const int b = blockIdx.x;
  const int dir = b & 1;
  const int nblk = (b & 7) >> 1;
  const int rt = b >> 3;
  const int t = dir ? (15 - s) : s;
  const int cnt = cnts[t];
  const int m0 = rt * 128;
  if (m0 >= cnt) return;

  const float* proj = dir ? proj_b : proj_f;
  const ush* whh = dir ? whhp_b : whhp_f;
  const ush* hr = dir ? hr_b : hr_f;
  ush* hw = dir ? hw_b : hw_f;
  float* cT = dir ? cT_b : cT_f;

  __shared__ __align__(128) unsigned char ldsA[128 * 128];  // 16 KB
  __shared__ __align__(128) unsigned char ldsB[256 * 128];  // 32 KB

  const int tid = threadIdx.x;
  const int lane = tid & 63;
  const int w = tid >> 6;
  const int wr = w >> 2, wc = w & 3;
  const int l8 = lane >> 3, l7 = lane & 7;
  const int frow = lane & 15, fkq = lane >> 4;

  // ---- epilogue prefetch: lens, tokens, c (independent of GEMM) ----
  const int j = nblk * 64 + wc * 16 + frow;
  int4 l4[4], tv4[4];
  f32x4 cv4[4];
#pragma unroll
  for (int fr = 0; fr < 4; ++fr) {
    const int n0 = m0 + wr * 64 + fr * 16 + fkq * 4;
    l4[fr] = *(const int4*)&plens[n0];
    tv4[fr] = *(const int4*)&tokperm[t * N_SEQ + n0];
    cv4[fr] = *(const f32x4*)&cT[(size_t)j * N_SEQ + n0];
  }

  // ---- staging offsets ----
  const int arow0 = 16 * w + l8, arow1 = arow0 + 8;
  const unsigned aoff0 = (unsigned)(m0 + arow0) * 256 + (l7 ^ (arow0 & 7)) * 8;
  const unsigned aoff1 = (unsigned)(m0 + arow1) * 256 + (l7 ^ (arow1 & 7)) * 8;
  unsigned boff[4];
#pragma unroll
  for (int jj = 0; jj < 4; ++jj) {
    const int brow = 32 * w + 8 * jj + l8;
    boff[jj] = (unsigned)(nblk * 256 + brow) * 256 + (l7 ^ (brow & 7)) * 8;
  }

  f32x4 acc[4][4] = {};
  for (int kt = 0; kt < 4; ++kt) {
    const int k0 = kt * 64;
    glds16(hr + aoff0 + k0, &ldsA[(16 * w) * 128]);
    glds16(hr + aoff1 + k0, &ldsA[(16 * w + 8) * 128]);
#pragma unroll
    for (int jj = 0; jj < 4; ++jj)
      glds16(whh + boff[jj] + k0, &ldsB[(32 * w + 8 * jj) * 128]);
    __syncthreads();
#pragma unroll
    for (int ksub = 0; ksub < 2; ++ksub) {
      bf16x8 av[4], bv[4];
#pragma unroll
      for (int fr = 0; fr < 4; ++fr) {
        const int row = wr * 64 + fr * 16 + frow;
        av[fr] = *(const bf16x8*)&ldsA[row * 128 + (((ksub * 4 + fkq) ^ (row & 7)) * 16)];
      }
#pragma unroll
      for (int fc = 0; fc < 4; ++fc) {
        const int row = wc * 64 + fc * 16 + frow;
        bv[fc] = *(const bf16x8*)&ldsB[row * 128 + (((ksub * 4 + fkq) ^ (row & 7)) * 16)];
      }
      __builtin_amdgcn_s_setprio(1);
#pragma unroll
      for (int fr = 0; fr < 4; ++fr)
#pragma unroll
        for (int fc = 0; fc < 4; ++fc)
          acc[fr][fc] = __builtin_amdgcn_mfma_f32_16x16x32_bf16(av[fr], bv[fc], acc[fr][fc], 0, 0, 0);
      __builtin_amdgcn_s_setprio(0);
    }
    __syncthreads();
  }

  // ---- epilogue: gates = acc + proj[tok] (bias folded), cell update, no copies ----
#pragma unroll
  for (int fr = 0; fr < 4; ++fr) {
    const int n0 = m0 + wr * 64 + fr * 16 + fkq * 4;
    const int4 ln = tv4[fr];  // tokens
    const int4 lv = l4[fr];   // lens
    const int lmax = max(max(lv.x, lv.y), max(lv.z, lv.w));
    if (t >= lmax) continue;  // whole group graduated: no writes at all
    f32x4 cv = cv4[fr];
    const f32x4 gi = acc[fr][0], gf = acc[fr][1], gg = acc[fr][2], go = acc[fr][3];
#pragma unroll
    for (int r = 0; r < 4; ++r) {
      const int lnv = (r == 0) ? lv.x : (r == 1) ? lv.y : (r == 2) ? lv.z : lv.w;
      if (t < lnv) {
        const int tvr = (r == 0) ? ln.x : (r == 1) ? ln.y : (r == 2) ? ln.z : ln.w;
        const f32x4 pr4 = *(const f32x4*)&proj[(size_t)tvr * 1024 + j * 4];
        const float iv = sigmoidf_(gi[r] + pr4[0]);
        const float fv = sigmoidf_(gf[r] + pr4[1]);
        const float gv = tanhf_(gg[r] + pr4[2]);
        const float ov = sigmoidf_(go[r] + pr4[3]);
        const bool first = dir ? (t == lnv - 1) : (t == 0);
        const float cn = fv * (first ? 0.0f : cv[r]) + iv * gv;
        cv[r] = cn;
        hw[(size_t)(n0 + r) * H_DIM + j] = f2bf(ov * tanhf_(cn));
      }
    }
    *(f32x4*)&cT[(size_t)j * N_SEQ + n0] = cv;
  }
}

// ---------------- segment-mean pool with per-row parity buffer select ----------------

__global__ __launch_bounds__(256) void k_pool(const ush* __restrict__ h0f, const ush* __restrict__ h1f,
                                              const ush* __restrict__ h0b,
                                              const int* __restrict__ pinv, const int* __restrict__ lens,
                                              const int* __restrict__ plen,
                                              float* __restrict__ pooled) {
  const int b = blockIdx.x, tid = threadIdx.x;
  int start = 0;
  for (int i = 0; i < b; ++i) start += plen[i];
  const int cnt = plen[b];
  float s0 = 0.f, s1 = 0.f;
  for (int r = 0; r < cnt; ++r) {
    const int n = start + r;
    const size_t pr = (size_t)pinv[n];
    const int l = lens[n];
    // fwd last write at s=l-1: s odd -> h0f, s even -> h1f  => l even -> h0f, l odd -> h1f
    const ush* hf = (l & 1) ? h1f : h0f;
    s0 += bf2f(hf[pr * H_DIM + tid]);
    s1 += bf2f(h0b[pr * H_DIM + tid]);  // bwd always ends at s=15 (odd) -> h0b
  }
  float inv = 1.0f / (float)cnt;
  pooled[b * 512 + tid] = s0 * inv;
  pooled[b * 512 + H_DIM + tid] = s1 * inv;
}

// ---------------- tiny linear (128x512x512) + L2 normalize, f32 ----------------

__global__ __launch_bounds__(256) void k_final(const float* __restrict__ pooled,
                                               const float* __restrict__ W,
                                               const float* __restrict__ bl,
                                               float* __restrict__ out) {
  const int b = blockIdx.x, tid = threadIdx.x;
  __shared__ float pv[512];
  __shared__ float pre[512];
  __shared__ float red[4];
  pv[tid] = pooled[b * 512 + tid];
  pv[tid + 256] = pooled[b * 512 + 256 + tid];
  __syncthreads();
#pragma unroll
  for (int half = 0; half < 2; ++half) {
    const int dd = tid + half * 256;
    const f32x4* wr = (const f32x4*)(W + (size_t)dd * 512);
    const f32x4* pvv = (const f32x4*)pv;
    float s = bl[dd];
#pragma unroll 4
    for (int k4 = 0; k4 < 128; ++k4) {
      f32x4 wv = wr[k4], xv = pvv[k4];
      s += wv[0] * xv[0] + wv[1] * xv[1] + wv[2] * xv[2] + wv[3] * xv[3];
    }
    pre[dd] = s;
  }
  __syncthreads();
  float ss = pre[tid] * pre[tid] + pre[tid + 256] * pre[tid + 256];
#pragma unroll
  for (int off = 32; off > 0; off >>= 1) ss += __shfl_down(ss, off, 64);
  if ((tid & 63) == 0) red[tid >> 6] = ss;
  __syncthreads();
  float tot = red[0] + red[1] + red[2] + red[3];
  float scale = 1.0f / fmaxf(sqrtf(tot), 1e-5f);
  out[b * 512 + tid] = pre[tid] * scale;
  out[b * 512 + 256 + tid] = pre[tid + 256] * scale;
}

// ---------------- launch ----------------

extern "C" void kernel_launch(void* const* d_in, const int* in_sizes, int n_in,
                              void* d_out, int out_size, void* d_ws, size_t ws_size,
                              hipStream_t stream) {
  const int* tok    = (const int*)d_in[0];
  const int* plen   = (const int*)d_in[1];
  const float* emb  = (const float*)d_in[2];
  const float* Wih_f = (const float*)d_in[3];
  const float* Whh_f = (const float*)d_in[4];
  const float* b_f   = (const float*)d_in[5];
  const float* Wih_b = (const float*)d_in[6];
  const float* Whh_b = (const float*)d_in[7];
  const float* b_b   = (const float*)d_in[8];
  const float* Wlin  = (const float*)d_in[9];
  const float* blin  = (const float*)d_in[10];
  float* out = (float*)d_out;

  char* ws = (char*)d_ws;
  size_t off = 0;
  auto alloc = [&](size_t bytes) {
    void* p = ws + off;
    off = (off + bytes + 255) & ~(size_t)255;
    return p;
  };
  ush* embbf   = (ush*)alloc((size_t)V_SIZE * E_DIM * 2);
  ush* wihpf   = (ush*)alloc((size_t)1024 * 256 * 2);
  ush* wihpb   = (ush*)alloc((size_t)1024 * 256 * 2);
  ush* whhpf   = (ush*)alloc((size_t)1024 * 256 * 2);
  ush* whhpb   = (ush*)alloc((size_t)1024 * 256 * 2);
  int* lens    = (int*)alloc((size_t)N_SEQ * 4);
  int* perm    = (int*)alloc((size_t)N_SEQ * 4);
  int* pinv    = (int*)alloc((size_t)N_SEQ * 4);
  int* plens   = (int*)alloc((size_t)N_SEQ * 4);
  int* tokperm = (int*)alloc((size_t)T_LEN * N_SEQ * 4);
  int* hist    = (int*)alloc(17 * 4);
  int* cursor  = (int*)alloc(17 * 4);
  int* cnts    = (int*)alloc(16 * 4);
  float* projf = (float*)alloc((size_t)V_SIZE * 1024 * 4);
  float* projb = (float*)alloc((size_t)V_SIZE * 1024 * 4);
  ush* h0f     = (ush*)alloc((size_t)N_SEQ * H_DIM * 2);
  ush* h1f     = (ush*)alloc((size_t)N_SEQ * H_DIM * 2);
  ush* h0b     = (ush*)alloc((size_t)N_SEQ * H_DIM * 2);
  ush* h1b     = (ush*)alloc((size_t)N_SEQ * H_DIM * 2);
  float* cTf   = (float*)alloc((size_t)H_DIM * N_SEQ * 4);
  float* cTb   = (float*)alloc((size_t)H_DIM * N_SEQ * 4);
  float* pooled = (float*)alloc((size_t)B_SAMP * 512 * 4);

  hipMemsetAsync(hist, 0, 17 * 4, stream);
  hipMemsetAsync(h0f, 0, (size_t)N_SEQ * H_DIM * 2, stream);
  hipMemsetAsync(h1f, 0, (size_t)N_SEQ * H_DIM * 2, stream);
  hipMemsetAsync(h0b, 0, (size_t)N_SEQ * H_DIM * 2, stream);
  hipMemsetAsync(h1b, 0, (size_t)N_SEQ * H_DIM * 2, stream);

  k_lens<<<N_SEQ / 256, 256, 0, stream>>>(tok, lens, hist);
  k_offsets<<<1, 64, 0, stream>>>(hist, cursor, cnts);
  k_scatter<<<N_SEQ / 256, 256, 0, stream>>>(lens, cursor, perm, pinv, plens);
  k_tokperm<<<(T_LEN * N_SEQ) / 256, 256, 0, stream>>>(tok, perm, tokperm);
  k_embcvt<<<(V_SIZE * E_DIM) / 256, 256, 0, stream>>>(emb, embbf);
  k_wprep<<<(2 * 2 * 1024 * 256) / 256, 256, 0, stream>>>(Wih_f, Whh_f, Wih_b, Whh_b,
                                                           wihpf, wihpb, whhpf, whhpb);
  k_vproj<<<dim3(79 * 4, 2), 512, 0, stream>>>(embbf, wihpf, wihpb, b_f, b_b, projf, projb);

  // grid 1024, XCD decode: b&1=dir, (b&7)>>1=nblk, b>>3=rt
  for (int s = 0; s < T_LEN; ++s) {
    const ush* hrf = (s & 1) ? h1f : h0f;
    ush* hwf       = (s & 1) ? h0f : h1f;
    const ush* hrb = (s & 1) ? h1b : h0b;
    ush* hwb       = (s & 1) ? h0b : h1b;
    k_step<<<1024, 512, 0, stream>>>(projf, projb, tokperm, plens, cnts, whhpf, whhpb,
                                     hrf, hwf, hrb, hwb, cTf, cTb, s);
  }
  k_pool<<<B_SAMP, 256, 0, stream>>>(h0f, h1f, h0b, pinv, lens, plen, pooled);
  k_final<<<B_SAMP, 256, 0, stream>>>(pooled, Wlin, blin, out);
}

// Round 14
// 845.247 us; speedup vs baseline: 1.5015x; 1.5015x over previous
//
#include <hip/hip_runtime.h>
#include <stdint.h>

#define N_SEQ 16384
#define T_LEN 16
#define E_DIM 256
#define H_DIM 256
#define K_DIM 512
#define B_SAMP 128
#define V_SIZE 10000

typedef __bf16 bf16x8 __attribute__((ext_vector_type(8)));
typedef float  f32x4  __attribute__((ext_vector_type(4)));
typedef unsigned short ush;

__device__ __forceinline__ ush f2bf(float x) {
  unsigned int u = __float_as_uint(x);
  u = (u + 0x7fffu + ((u >> 16) & 1u)) >> 16;
  return (ush)u;
}
__device__ __forceinline__ float bf2f(ush v) {
  return __uint_as_float(((unsigned int)v) << 16);
}
__device__ __forceinline__ float sigmoidf_(float x) {
  return 1.0f / (1.0f + __expf(-x));
}
__device__ __forceinline__ float tanhf_(float x) {
  float e = __expf(2.0f * x);
  return 1.0f - 2.0f / (e + 1.0f);
}
__device__ __forceinline__ void glds16(const void* g, const void* l) {
  __builtin_amdgcn_global_load_lds(
      (const __attribute__((address_space(1))) unsigned int*)g,
      (__attribute__((address_space(3))) unsigned int*)l, 16, 0, 0);
}

// ---------------- prep kernels ----------------

__global__ __launch_bounds__(256) void k_lens(const int* __restrict__ tok, int* __restrict__ lens,
                                              int* __restrict__ hist) {
  __shared__ int lh[17];
  if (threadIdx.x < 17) lh[threadIdx.x] = 0;
  __syncthreads();
  int n = blockIdx.x * 256 + threadIdx.x;
  const int* r = tok + n * T_LEN;
  int c = 0;
#pragma unroll
  for (int t = 0; t < T_LEN; ++t) c += (r[t] != 0);
  lens[n] = c;
  atomicAdd(&lh[c], 1);
  __syncthreads();
  if (threadIdx.x < 17 && lh[threadIdx.x]) atomicAdd(&hist[threadIdx.x], lh[threadIdx.x]);
}

// descending-length bucket starts; cnts[t] = count(len > t): active prefix for both dirs
// (parity pooling: no graduation copies needed anywhere)
__global__ void k_offsets(const int* __restrict__ hist, int* __restrict__ cursor,
                          int* __restrict__ cnts) {
  if (threadIdx.x == 0) {
    int off = 0;
    for (int l = 16; l >= 0; --l) { cursor[l] = off; off += hist[l]; }
    for (int t = 0; t < 16; ++t) {
      int c = 0;
      for (int l = t + 1; l <= 16; ++l) c += hist[l];
      cnts[t] = c;
    }
  }
}

__global__ __launch_bounds__(256) void k_scatter(const int* __restrict__ lens, int* __restrict__ cursor,
                                                 int* __restrict__ perm, int* __restrict__ pinv,
                                                 int* __restrict__ plens) {
  int n = blockIdx.x * 256 + threadIdx.x;
  int l = lens[n];
  int pos = atomicAdd(&cursor[l], 1);
  perm[pos] = n;
  pinv[n] = pos;
  plens[pos] = l;
}

// gather form: coalesced writes; tok (1 MB) is L2-resident
__global__ __launch_bounds__(256) void k_tokperm(const int* __restrict__ tok, const int* __restrict__ perm,
                                                 int* __restrict__ tokperm) {
  int id = blockIdx.x * 256 + threadIdx.x;  // < T_LEN * N_SEQ
  int t = id >> 14;                          // N_SEQ = 2^14
  int pos = id & (N_SEQ - 1);
  tokperm[id] = tok[perm[pos] * T_LEN + t];
}

__global__ __launch_bounds__(256) void k_embcvt(const float* __restrict__ emb, ush* __restrict__ out) {
  int i = blockIdx.x * 256 + threadIdx.x;
  out[i] = f2bf(emb[i]);
}

// Permuted weights: wpt[p][k], p = nb*256 + wc*64 + q*16 + jj  <->
// gate-row r = q*256 + (nb*64 + wc*16 + jj);  k<256 -> W_ih[r][k], else W_hh[r][k-256].
__global__ __launch_bounds__(256) void k_wprep(const float* __restrict__ Wih_f, const float* __restrict__ Whh_f,
                                               const float* __restrict__ Wih_b, const float* __restrict__ Whh_b,
                                               ush* __restrict__ wpt_f, ush* __restrict__ wpt_b) {
  int id = blockIdx.x * 256 + threadIdx.x;  // < 2*1024*512
  int dir = id >> 19;
  int rem = id & ((1 << 19) - 1);
  int p = rem >> 9;
  int k = rem & 511;
  int nb = p >> 8, wc = (p >> 6) & 3, q = (p >> 4) & 3, jj = p & 15;
  int r = q * 256 + nb * 64 + wc * 16 + jj;
  const float* Wih = dir ? Wih_b : Wih_f;
  const float* Whh = dir ? Whh_b : Whh_f;
  float v = (k < 256) ? Wih[r * 256 + k] : Whh[r * 256 + (k - 256)];
  ush* o = dir ? wpt_b : wpt_f;
  o[p * 512 + k] = f2bf(v);
}

// ---------------- LSTM step: K=512 fused GEMM + cell update (R3 core, measured best) ----------------
// grid(512,2): mblk = bid.x>>2, nblk = bid.x&3, dir = bid.y. Length-sorted rows;
// active prefix cnts[t] = count(len>t); blocks past it exit. 512 thr / 8 waves (2x4),
// tile 128 rows x 256 pcols, K=512 in 8 chunks of 64; XOR-swizzled LDS (measured
// conflict-free); glds16 staging; 2 barriers/chunk. Parity pooling: NO graduation
// copies; first-active-step c init (no c memsets).

__global__ __launch_bounds__(512, 4)
void k_step(const ush* __restrict__ embbf, const int* __restrict__ tokperm,
            const int* __restrict__ plens, const int* __restrict__ cnts,
            const ush* __restrict__ wpt_f, const ush* __restrict__ wpt_b,
            const float* __restrict__ bias_f, const float* __restrict__ bias_b,
            const ush* __restrict__ hr_f, ush* __restrict__ hw_f,
            const ush* __restrict__ hr_b, ush* __restrict__ hw_b,
            float* __restrict__ c_f, float* __restrict__ c_b,
            int s) {
  const int dir = blockIdx.y;
  const int t = dir ? (15 - s) : s;
  const int cnt = cnts[t];
  const int mblk = blockIdx.x >> 2;
  const int m0 = mblk * 128;
  if (m0 >= cnt) return;

  const int nblk = blockIdx.x & 3;
  const ush* wpt = dir ? wpt_b : wpt_f;
  const float* bias = dir ? bias_b : bias_f;
  const ush* hr = dir ? hr_b : hr_f;
  ush* hw = dir ? hw_b : hw_f;
  float* cc = dir ? c_b : c_f;

  __shared__ __align__(128) unsigned char ldsA[128 * 128];  // 16 KB
  __shared__ __align__(128) unsigned char ldsB[256 * 128];  // 32 KB

  const int tid = threadIdx.x;
  const int lane = tid & 63;
  const int w = tid >> 6;
  const int wr = w >> 2;
  const int wc = w & 3;

  // ---- staging address precompute (element offsets, fixed per thread) ----
  const int l8 = lane >> 3;        // sub-row within 8-row group
  const int l7 = lane & 7;         // chunk slot in LDS
  const int arow0 = 16 * w + l8;
  const int arow1 = arow0 + 8;
  const int ach0 = l7 ^ (arow0 & 7);
  const int ach1 = l7 ^ (arow1 & 7);
  const unsigned aoffE0 = (unsigned)tokperm[t * N_SEQ + m0 + arow0] * E_DIM + ach0 * 8;
  const unsigned aoffE1 = (unsigned)tokperm[t * N_SEQ + m0 + arow1] * E_DIM + ach1 * 8;
  const unsigned aoffH0 = (unsigned)(m0 + arow0) * H_DIM + ach0 * 8;
  const unsigned aoffH1 = (unsigned)(m0 + arow1) * H_DIM + ach1 * 8;
  unsigned boff[4];
#pragma unroll
  for (int jj = 0; jj < 4; ++jj) {
    const int brow = 32 * w + 8 * jj + l8;
    const int bch = l7 ^ (brow & 7);
    boff[jj] = (unsigned)(nblk * 256 + brow) * K_DIM + bch * 8;
  }

  f32x4 acc[4][4] = {};
  const int frow = lane & 15;
  const int fkq = lane >> 4;  // 0..3

  for (int kt = 0; kt < 8; ++kt) {
    const int k0 = kt * 64;
    if (kt < 4) {
      glds16(embbf + aoffE0 + k0, &ldsA[(16 * w) * 128]);
      glds16(embbf + aoffE1 + k0, &ldsA[(16 * w + 8) * 128]);
    } else {
      glds16(hr + aoffH0 + (k0 - E_DIM), &ldsA[(16 * w) * 128]);
      glds16(hr + aoffH1 + (k0 - E_DIM), &ldsA[(16 * w + 8) * 128]);
    }
#pragma unroll
    for (int jj = 0; jj < 4; ++jj)
      glds16(wpt + boff[jj] + k0, &ldsB[(32 * w + 8 * jj) * 128]);
    __syncthreads();
#pragma unroll
    for (int ksub = 0; ksub < 2; ++ksub) {
      bf16x8 av[4], bv[4];
#pragma unroll
      for (int fr = 0; fr < 4; ++fr) {
        const int row = wr * 64 + fr * 16 + frow;
        const int ch = (ksub * 4 + fkq) ^ (row & 7);
        av[fr] = *(const bf16x8*)&ldsA[row * 128 + ch * 16];
      }
#pragma unroll
      for (int fc = 0; fc < 4; ++fc) {
        const int row = wc * 64 + fc * 16 + frow;
        const int ch = (ksub * 4 + fkq) ^ (row & 7);
        bv[fc] = *(const bf16x8*)&ldsB[row * 128 + ch * 16];
      }
#pragma unroll
      for (int fr = 0; fr < 4; ++fr)
#pragma unroll
        for (int fc = 0; fc < 4; ++fc)
          acc[fr][fc] = __builtin_amdgcn_mfma_f32_16x16x32_bf16(av[fr], bv[fc], acc[fr][fc], 0, 0, 0);
    }
    __syncthreads();
  }

  // ---- fused LSTM cell update: fc = gate (i,f,g,o) for hidden unit j; no copies ----
  const int j = nblk * 64 + wc * 16 + frow;
  const float b0 = bias[j], b1 = bias[256 + j], b2 = bias[512 + j], b3 = bias[768 + j];
#pragma unroll
  for (int fr = 0; fr < 4; ++fr) {
    const int n0 = m0 + wr * 64 + fr * 16 + fkq * 4;
    const int4 l4 = *(const int4*)&plens[n0];
    const f32x4 gi = acc[fr][0], gf = acc[fr][1], gg = acc[fr][2], go = acc[fr][3];
#pragma unroll
    for (int r = 0; r < 4; ++r) {
      const int lnv = (r == 0) ? l4.x : (r == 1) ? l4.y : (r == 2) ? l4.z : l4.w;
      if (t < lnv) {
        const size_t idx = (size_t)(n0 + r) * H_DIM + j;
        const float iv = sigmoidf_(gi[r] + b0);
        const float fv = sigmoidf_(gf[r] + b1);
        const float gv = tanhf_(gg[r] + b2);
        const float ov = sigmoidf_(go[r] + b3);
        const bool first = dir ? (t == lnv - 1) : (t == 0);
        const float cn = fv * (first ? 0.0f : cc[idx]) + iv * gv;
        cc[idx] = cn;
        hw[idx] = f2bf(ov * tanhf_(cn));
      }
    }
  }
}

// ---------------- segment-mean pool with per-row parity buffer select ----------------

__global__ __launch_bounds__(256) void k_pool(const ush* __restrict__ h0f, const ush* __restrict__ h1f,
                                              const ush* __restrict__ h0b,
                                              const int* __restrict__ pinv, const int* __restrict__ lens,
                                              const int* __restrict__ plen,
                                              float* __restrict__ pooled) {
  const int b = blockIdx.x, tid = threadIdx.x;
  int start = 0;
  for (int i = 0; i < b; ++i) start += plen[i];
  const int cnt = plen[b];
  float s0 = 0.f, s1 = 0.f;
  for (int r = 0; r < cnt; ++r) {
    const int n = start + r;
    const size_t pr = (size_t)pinv[n];
    const int l = lens[n];
    // fwd last write at s=l-1: s even -> h1f, s odd -> h0f  => l odd -> h1f, l even -> h0f
    const ush* hf = (l & 1) ? h1f : h0f;
    s0 += bf2f(hf[pr * H_DIM + tid]);
    s1 += bf2f(h0b[pr * H_DIM + tid]);  // bwd always last-written at s=15 (odd) -> h0b
  }
  float inv = 1.0f / (float)cnt;
  pooled[b * 512 + tid] = s0 * inv;
  pooled[b * 512 + H_DIM + tid] = s1 * inv;
}

// ---------------- tiny linear (128x512x512) + L2 normalize, f32 ----------------

__global__ __launch_bounds__(256) void k_final(const float* __restrict__ pooled,
                                               const float* __restrict__ W,
                                               const float* __restrict__ bl,
                                               float* __restrict__ out) {
  const int b = blockIdx.x, tid = threadIdx.x;
  __shared__ float pv[512];
  __shared__ float pre[512];
  __shared__ float red[4];
  pv[tid] = pooled[b * 512 + tid];
  pv[tid + 256] = pooled[b * 512 + 256 + tid];
  __syncthreads();
#pragma unroll
  for (int half = 0; half < 2; ++half) {
    const int dd = tid + half * 256;
    const f32x4* wr = (const f32x4*)(W + (size_t)dd * 512);
    const f32x4* pvv = (const f32x4*)pv;
    float s = bl[dd];
#pragma unroll 4
    for (int k4 = 0; k4 < 128; ++k4) {
      f32x4 wv = wr[k4], xv = pvv[k4];
      s += wv[0] * xv[0] + wv[1] * xv[1] + wv[2] * xv[2] + wv[3] * xv[3];
    }
    pre[dd] = s;
  }
  __syncthreads();
  float ss = pre[tid] * pre[tid] + pre[tid + 256] * pre[tid + 256];
#pragma unroll
  for (int off = 32; off > 0; off >>= 1) ss += __shfl_down(ss, off, 64);
  if ((tid & 63) == 0) red[tid >> 6] = ss;
  __syncthreads();
  float tot = red[0] + red[1] + red[2] + red[3];
  float scale = 1.0f / fmaxf(sqrtf(tot), 1e-5f);
  out[b * 512 + tid] = pre[tid] * scale;
  out[b * 512 + 256 + tid] = pre[tid + 256] * scale;
}

// ---------------- launch ----------------

extern "C" void kernel_launch(void* const* d_in, const int* in_sizes, int n_in,
                              void* d_out, int out_size, void* d_ws, size_t ws_size,
                              hipStream_t stream) {
  const int* tok    = (const int*)d_in[0];
  const int* plen   = (const int*)d_in[1];
  const float* emb  = (const float*)d_in[2];
  const float* Wih_f = (const float*)d_in[3];
  const float* Whh_f = (const float*)d_in[4];
  const float* b_f   = (const float*)d_in[5];
  const float* Wih_b = (const float*)d_in[6];
  const float* Whh_b = (const float*)d_in[7];
  const float* b_b   = (const float*)d_in[8];
  const float* Wlin  = (const float*)d_in[9];
  const float* blin  = (const float*)d_in[10];
  float* out = (float*)d_out;

  char* ws = (char*)d_ws;
  size_t off = 0;
  auto alloc = [&](size_t bytes) {
    void* p = ws + off;
    off = (off + bytes + 255) & ~(size_t)255;
    return p;
  };
  ush* embbf   = (ush*)alloc((size_t)V_SIZE * E_DIM * 2);
  ush* wptf    = (ush*)alloc((size_t)1024 * K_DIM * 2);
  ush* wptb    = (ush*)alloc((size_t)1024 * K_DIM * 2);
  int* lens    = (int*)alloc((size_t)N_SEQ * 4);
  int* perm    = (int*)alloc((size_t)N_SEQ * 4);
  int* pinv    = (int*)alloc((size_t)N_SEQ * 4);
  int* plens   = (int*)alloc((size_t)N_SEQ * 4);
  int* tokperm = (int*)alloc((size_t)T_LEN * N_SEQ * 4);
  int* hist    = (int*)alloc(17 * 4);
  int* cursor  = (int*)alloc(17 * 4);
  int* cnts    = (int*)alloc(16 * 4);
  ush* h0f     = (ush*)alloc((size_t)N_SEQ * H_DIM * 2);
  ush* h1f     = (ush*)alloc((size_t)N_SEQ * H_DIM * 2);
  ush* h0b     = (ush*)alloc((size_t)N_SEQ * H_DIM * 2);
  ush* h1b     = (ush*)alloc((size_t)N_SEQ * H_DIM * 2);
  float* cf    = (float*)alloc((size_t)N_SEQ * H_DIM * 4);
  float* cb    = (float*)alloc((size_t)N_SEQ * H_DIM * 4);
  float* pooled = (float*)alloc((size_t)B_SAMP * 512 * 4);

  hipMemsetAsync(hist, 0, 17 * 4, stream);
  hipMemsetAsync(h0f, 0, (size_t)N_SEQ * H_DIM * 2, stream);
  hipMemsetAsync(h1f, 0, (size_t)N_SEQ * H_DIM * 2, stream);
  hipMemsetAsync(h0b, 0, (size_t)N_SEQ * H_DIM * 2, stream);
  hipMemsetAsync(h1b, 0, (size_t)N_SEQ * H_DIM * 2, stream);

  k_lens<<<N_SEQ / 256, 256, 0, stream>>>(tok, lens, hist);
  k_offsets<<<1, 64, 0, stream>>>(hist, cursor, cnts);
  k_scatter<<<N_SEQ / 256, 256, 0, stream>>>(lens, cursor, perm, pinv, plens);
  k_tokperm<<<(T_LEN * N_SEQ) / 256, 256, 0, stream>>>(tok, perm, tokperm);
  k_embcvt<<<(V_SIZE * E_DIM) / 256, 256, 0, stream>>>(emb, embbf);
  k_wprep<<<(2 * 1024 * K_DIM) / 256, 256, 0, stream>>>(Wih_f, Whh_f, Wih_b, Whh_b, wptf, wptb);

  dim3 grid(512, 2);
  for (int s = 0; s < T_LEN; ++s) {
    const ush* hrf = (s & 1) ? h1f : h0f;
    ush* hwf       = (s & 1) ? h0f : h1f;
    const ush* hrb = (s & 1) ? h1b : h0b;
    ush* hwb       = (s & 1) ? h0b : h1b;
    k_step<<<grid, 512, 0, stream>>>(embbf, tokperm, plens, cnts, wptf, wptb,
                                     b_f, b_b, hrf, hwf, hrb, hwb, cf, cb, s);
  }
  k_pool<<<B_SAMP, 256, 0, stream>>>(h0f, h1f, h0b, pinv, lens, plen, pooled);
  k_final<<<B_SAMP, 256, 0, stream>>>(pooled, Wlin, blin, out);
}

// Round 15
// 816.458 us; speedup vs baseline: 1.5544x; 1.0353x over previous
//
#include <hip/hip_runtime.h>
#include <stdint.h>

#define N_SEQ 16384
#define T_LEN 16
#define E_DIM 256
#define H_DIM 256
#define K_DIM 512
#define B_SAMP 128
#define V_SIZE 10000
#define NBLK_LENS (N_SEQ / 256)

typedef __bf16 bf16x8 __attribute__((ext_vector_type(8)));
typedef float  f32x4  __attribute__((ext_vector_type(4)));
typedef unsigned short ush;

__device__ __forceinline__ ush f2bf(float x) {
  unsigned int u = __float_as_uint(x);
  u = (u + 0x7fffu + ((u >> 16) & 1u)) >> 16;
  return (ush)u;
}
__device__ __forceinline__ float bf2f(ush v) {
  return __uint_as_float(((unsigned int)v) << 16);
}
__device__ __forceinline__ float sigmoidf_(float x) {
  return 1.0f / (1.0f + __expf(-x));
}
__device__ __forceinline__ float tanhf_(float x) {
  float e = __expf(2.0f * x);
  return 1.0f - 2.0f / (e + 1.0f);
}
__device__ __forceinline__ void glds16(const void* g, const void* l) {
  __builtin_amdgcn_global_load_lds(
      (const __attribute__((address_space(1))) unsigned int*)g,
      (__attribute__((address_space(3))) unsigned int*)l, 16, 0, 0);
}

// ---------------- prep kernels ----------------

// lens + per-block histogram (no global atomics)
__global__ __launch_bounds__(256) void k_lens(const int* __restrict__ tok, int* __restrict__ lens,
                                              int* __restrict__ blockhist) {
  __shared__ int lh[17];
  if (threadIdx.x < 17) lh[threadIdx.x] = 0;
  __syncthreads();
  int n = blockIdx.x * 256 + threadIdx.x;
  const int* r = tok + n * T_LEN;
  int c = 0;
#pragma unroll
  for (int t = 0; t < T_LEN; ++t) c += (r[t] != 0);
  lens[n] = c;
  atomicAdd(&lh[c], 1);  // LDS atomic: cheap
  __syncthreads();
  if (threadIdx.x < 17) blockhist[blockIdx.x * 17 + threadIdx.x] = lh[threadIdx.x];
}

// descending-length bucket starts + per-block bases + cnts[t] = count(len > t)
__global__ void k_offsets(const int* __restrict__ blockhist, int* __restrict__ base,
                          int* __restrict__ cnts) {
  if (threadIdx.x == 0) {
    int tot[17];
    for (int l = 0; l <= 16; ++l) {
      int s = 0;
      for (int b = 0; b < NBLK_LENS; ++b) s += blockhist[b * 17 + l];
      tot[l] = s;
    }
    int start[17];
    int off = 0;
    for (int l = 16; l >= 0; --l) { start[l] = off; off += tot[l]; }
    for (int l = 0; l <= 16; ++l) {
      int run = start[l];
      for (int b = 0; b < NBLK_LENS; ++b) { base[b * 17 + l] = run; run += blockhist[b * 17 + l]; }
    }
    for (int t = 0; t < 16; ++t) {
      int c = 0;
      for (int l = t + 1; l <= 16; ++l) c += tot[l];
      cnts[t] = c;
    }
  }
}

// rank via LDS atomics + per-block base (no global atomic contention)
__global__ __launch_bounds__(256) void k_scatter(const int* __restrict__ lens, const int* __restrict__ base,
                                                 int* __restrict__ perm, int* __restrict__ pinv,
                                                 int* __restrict__ plens) {
  __shared__ int lh[17];
  if (threadIdx.x < 17) lh[threadIdx.x] = 0;
  __syncthreads();
  int n = blockIdx.x * 256 + threadIdx.x;
  int l = lens[n];
  int lr = atomicAdd(&lh[l], 1);
  int pos = base[blockIdx.x * 17 + l] + lr;
  perm[pos] = n;
  pinv[n] = pos;
  plens[pos] = l;
}

// gather form: coalesced writes; tok (1 MB) is L2-resident
__global__ __launch_bounds__(256) void k_tokperm(const int* __restrict__ tok, const int* __restrict__ perm,
                                                 int* __restrict__ tokperm) {
  int id = blockIdx.x * 256 + threadIdx.x;  // < T_LEN * N_SEQ
  int t = id >> 14;                          // N_SEQ = 2^14
  int pos = id & (N_SEQ - 1);
  tokperm[id] = tok[perm[pos] * T_LEN + t];
}

__global__ __launch_bounds__(256) void k_embcvt(const float* __restrict__ emb, ush* __restrict__ out) {
  int i = blockIdx.x * 256 + threadIdx.x;
  out[i] = f2bf(emb[i]);
}

// Permuted weights: wpt[p][k], p = nb*256 + wc*64 + q*16 + jj  <->
// gate-row r = q*256 + (nb*64 + wc*16 + jj);  k<256 -> W_ih[r][k], else W_hh[r][k-256].
__global__ __launch_bounds__(256) void k_wprep(const float* __restrict__ Wih_f, const float* __restrict__ Whh_f,
                                               const float* __restrict__ Wih_b, const float* __restrict__ Whh_b,
                                               ush* __restrict__ wpt_f, ush* __restrict__ wpt_b) {
  int id = blockIdx.x * 256 + threadIdx.x;  // < 2*1024*512
  int dir = id >> 19;
  int rem = id & ((1 << 19) - 1);
  int p = rem >> 9;
  int k = rem & 511;
  int nb = p >> 8, wc = (p >> 6) & 3, q = (p >> 4) & 3, jj = p & 15;
  int r = q * 256 + nb * 64 + wc * 16 + jj;
  const float* Wih = dir ? Wih_b : Wih_f;
  const float* Whh = dir ? Whh_b : Whh_f;
  float v = (k < 256) ? Wih[r * 256 + k] : Whh[r * 256 + (k - 256)];
  ush* o = dir ? wpt_b : wpt_f;
  o[p * 512 + k] = f2bf(v);
}

// ---------------- LSTM step: K=512 fused GEMM + cell update (R14 core, measured best) ----------------
// grid(512,2): mblk = bid.x>>2, nblk = bid.x&3, dir = bid.y. Length-sorted rows;
// active prefix cnts[t] = count(len>t); blocks past it exit. 512 thr / 8 waves (2x4),
// tile 128 rows x 256 pcols, K=512 in 8 chunks of 64; XOR-swizzled LDS (measured
// conflict-free); glds16 staging; 2 barriers/chunk. Parity pooling: NO graduation
// copies; first-active-step c init (no c memsets).

__global__ __launch_bounds__(512, 4)
void k_step(const ush* __restrict__ embbf, const int* __restrict__ tokperm,
            const int* __restrict__ plens, const int* __restrict__ cnts,
            const ush* __restrict__ wpt_f, const ush* __restrict__ wpt_b,
            const float* __restrict__ bias_f, const float* __restrict__ bias_b,
            const ush* __restrict__ hr_f, ush* __restrict__ hw_f,
            const ush* __restrict__ hr_b, ush* __restrict__ hw_b,
            float* __restrict__ c_f, float* __restrict__ c_b,
            int s) {
  const int dir = blockIdx.y;
  const int t = dir ? (15 - s) : s;
  const int cnt = cnts[t];
  const int mblk = blockIdx.x >> 2;
  const int m0 = mblk * 128;
  if (m0 >= cnt) return;

  const int nblk = blockIdx.x & 3;
  const ush* wpt = dir ? wpt_b : wpt_f;
  const float* bias = dir ? bias_b : bias_f;
  const ush* hr = dir ? hr_b : hr_f;
  ush* hw = dir ? hw_b : hw_f;
  float* cc = dir ? c_b : c_f;

  __shared__ __align__(128) unsigned char ldsA[128 * 128];  // 16 KB
  __shared__ __align__(128) unsigned char ldsB[256 * 128];  // 32 KB

  const int tid = threadIdx.x;
  const int lane = tid & 63;
  const int w = tid >> 6;
  const int wr = w >> 2;
  const int wc = w & 3;

  // ---- staging address precompute (element offsets, fixed per thread) ----
  const int l8 = lane >> 3;        // sub-row within 8-row group
  const int l7 = lane & 7;         // chunk slot in LDS
  const int arow0 = 16 * w + l8;
  const int arow1 = arow0 + 8;
  const int ach0 = l7 ^ (arow0 & 7);
  const int ach1 = l7 ^ (arow1 & 7);
  const unsigned aoffE0 = (unsigned)tokperm[t * N_SEQ + m0 + arow0] * E_DIM + ach0 * 8;
  const unsigned aoffE1 = (unsigned)tokperm[t * N_SEQ + m0 + arow1] * E_DIM + ach1 * 8;
  const unsigned aoffH0 = (unsigned)(m0 + arow0) * H_DIM + ach0 * 8;
  const unsigned aoffH1 = (unsigned)(m0 + arow1) * H_DIM + ach1 * 8;
  unsigned boff[4];
#pragma unroll
  for (int jj = 0; jj < 4; ++jj) {
    const int brow = 32 * w + 8 * jj + l8;
    const int bch = l7 ^ (brow & 7);
    boff[jj] = (unsigned)(nblk * 256 + brow) * K_DIM + bch * 8;
  }

  f32x4 acc[4][4] = {};
  const int frow = lane & 15;
  const int fkq = lane >> 4;  // 0..3

  for (int kt = 0; kt < 8; ++kt) {
    const int k0 = kt * 64;
    if (kt < 4) {
      glds16(embbf + aoffE0 + k0, &ldsA[(16 * w) * 128]);
      glds16(embbf + aoffE1 + k0, &ldsA[(16 * w + 8) * 128]);
    } else {
      glds16(hr + aoffH0 + (k0 - E_DIM), &ldsA[(16 * w) * 128]);
      glds16(hr + aoffH1 + (k0 - E_DIM), &ldsA[(16 * w + 8) * 128]);
    }
#pragma unroll
    for (int jj = 0; jj < 4; ++jj)
      glds16(wpt + boff[jj] + k0, &ldsB[(32 * w + 8 * jj) * 128]);
    __syncthreads();
#pragma unroll
    for (int ksub = 0; ksub < 2; ++ksub) {
      bf16x8 av[4], bv[4];
#pragma unroll
      for (int fr = 0; fr < 4; ++fr) {
        const int row = wr * 64 + fr * 16 + frow;
        const int ch = (ksub * 4 + fkq) ^ (row & 7);
        av[fr] = *(const bf16x8*)&ldsA[row * 128 + ch * 16];
      }
#pragma unroll
      for (int fc = 0; fc < 4; ++fc) {
        const int row = wc * 64 + fc * 16 + frow;
        const int ch = (ksub * 4 + fkq) ^ (row & 7);
        bv[fc] = *(const bf16x8*)&ldsB[row * 128 + ch * 16];
      }
#pragma unroll
      for (int fr = 0; fr < 4; ++fr)
#pragma unroll
        for (int fc = 0; fc < 4; ++fc)
          acc[fr][fc] = __builtin_amdgcn_mfma_f32_16x16x32_bf16(av[fr], bv[fc], acc[fr][fc], 0, 0, 0);
    }
    __syncthreads();
  }

  // ---- fused LSTM cell update: fc = gate (i,f,g,o) for hidden unit j; no copies ----
  const int j = nblk * 64 + wc * 16 + frow;
  const float b0 = bias[j], b1 = bias[256 + j], b2 = bias[512 + j], b3 = bias[768 + j];
#pragma unroll
  for (int fr = 0; fr < 4; ++fr) {
    const int n0 = m0 + wr * 64 + fr * 16 + fkq * 4;
    const int4 l4 = *(const int4*)&plens[n0];
    const f32x4 gi = acc[fr][0], gf = acc[fr][1], gg = acc[fr][2], go = acc[fr][3];
#pragma unroll
    for (int r = 0; r < 4; ++r) {
      const int lnv = (r == 0) ? l4.x : (r == 1) ? l4.y : (r == 2) ? l4.z : l4.w;
      if (t < lnv) {
        const size_t idx = (size_t)(n0 + r) * H_DIM + j;
        const float iv = sigmoidf_(gi[r] + b0);
        const float fv = sigmoidf_(gf[r] + b1);
        const float gv = tanhf_(gg[r] + b2);
        const float ov = sigmoidf_(go[r] + b3);
        const bool first = dir ? (t == lnv - 1) : (t == 0);
        const float cn = fv * (first ? 0.0f : cc[idx]) + iv * gv;
        cc[idx] = cn;
        hw[idx] = f2bf(ov * tanhf_(cn));
      }
    }
  }
}

// ---------------- segment-mean pool with per-row parity buffer select ----------------

__global__ __launch_bounds__(256) void k_pool(const ush* __restrict__ h0f, const ush* __restrict__ h1f,
                                              const ush* __restrict__ h0b,
                                              const int* __restrict__ pinv, const int* __restrict__ lens,
                                              const int* __restrict__ plen,
                                              float* __restrict__ pooled) {
  const int b = blockIdx.x, tid = threadIdx.x;
  int start = 0;
  for (int i = 0; i < b; ++i) start += plen[i];
  const int cnt = plen[b];
  float s0 = 0.f, s1 = 0.f;
  for (int r = 0; r < cnt; ++r) {
    const int n = start + r;
    const size_t pr = (size_t)pinv[n];
    const int l = lens[n];
    // fwd last write at s=l-1: s even -> h1f, s odd -> h0f  => l odd -> h1f, l even -> h0f
    const ush* hf = (l & 1) ? h1f : h0f;
    s0 += bf2f(hf[pr * H_DIM + tid]);
    s1 += bf2f(h0b[pr * H_DIM + tid]);  // bwd always last-written at s=15 (odd) -> h0b
  }
  float inv = 1.0f / (float)cnt;
  pooled[b * 512 + tid] = s0 * inv;
  pooled[b * 512 + H_DIM + tid] = s1 * inv;
}

// ---------------- tiny linear (128x512x512) + L2 normalize, f32 ----------------

__global__ __launch_bounds__(256) void k_final(const float* __restrict__ pooled,
                                               const float* __restrict__ W,
                                               const float* __restrict__ bl,
                                               float* __restrict__ out) {
  const int b = blockIdx.x, tid = threadIdx.x;
  __shared__ float pv[512];
  __shared__ float pre[512];
  __shared__ float red[4];
  pv[tid] = pooled[b * 512 + tid];
  pv[tid + 256] = pooled[b * 512 + 256 + tid];
  __syncthreads();
#pragma unroll
  for (int half = 0; half < 2; ++half) {
    const int dd = tid + half * 256;
    const f32x4* wr = (const f32x4*)(W + (size_t)dd * 512);
    const f32x4* pvv = (const f32x4*)pv;
    float s = bl[dd];
#pragma unroll 4
    for (int k4 = 0; k4 < 128; ++k4) {
      f32x4 wv = wr[k4], xv = pvv[k4];
      s += wv[0] * xv[0] + wv[1] * xv[1] + wv[2] * xv[2] + wv[3] * xv[3];
    }
    pre[dd] = s;
  }
  __syncthreads();
  float ss = pre[tid] * pre[tid] + pre[tid + 256] * pre[tid + 256];
#pragma unroll
  for (int off = 32; off > 0; off >>= 1) ss += __shfl_down(ss, off, 64);
  if ((tid & 63) == 0) red[tid >> 6] = ss;
  __syncthreads();
  float tot = red[0] + red[1] + red[2] + red[3];
  float scale = 1.0f / fmaxf(sqrtf(tot), 1e-5f);
  out[b * 512 + tid] = pre[tid] * scale;
  out[b * 512 + 256 + tid] = pre[tid + 256] * scale;
}

// ---------------- launch ----------------

extern "C" void kernel_launch(void* const* d_in, const int* in_sizes, int n_in,
                              void* d_out, int out_size, void* d_ws, size_t ws_size,
                              hipStream_t stream) {
  const int* tok    = (const int*)d_in[0];
  const int* plen   = (const int*)d_in[1];
  const float* emb  = (const float*)d_in[2];
  const float* Wih_f = (const float*)d_in[3];
  const float* Whh_f = (const float*)d_in[4];
  const float* b_f   = (const float*)d_in[5];
  const float* Wih_b = (const float*)d_in[6];
  const float* Whh_b = (const float*)d_in[7];
  const float* b_b   = (const float*)d_in[8];
  const float* Wlin  = (const float*)d_in[9];
  const float* blin  = (const float*)d_in[10];
  float* out = (float*)d_out;

  char* ws = (char*)d_ws;
  size_t off = 0;
  auto alloc = [&](size_t bytes) {
    void* p = ws + off;
    off = (off + bytes + 255) & ~(size_t)255;
    return p;
  };
  ush* embbf   = (ush*)alloc((size_t)V_SIZE * E_DIM * 2);
  ush* wptf    = (ush*)alloc((size_t)1024 * K_DIM * 2);
  ush* wptb    = (ush*)alloc((size_t)1024 * K_DIM * 2);
  int* lens    = (int*)alloc((size_t)N_SEQ * 4);
  int* perm    = (int*)alloc((size_t)N_SEQ * 4);
  int* pinv    = (int*)alloc((size_t)N_SEQ * 4);
  int* plens   = (int*)alloc((size_t)N_SEQ * 4);
  int* tokperm = (int*)alloc((size_t)T_LEN * N_SEQ * 4);
  int* blockhist = (int*)alloc((size_t)NBLK_LENS * 17 * 4);
  int* base    = (int*)alloc((size_t)NBLK_LENS * 17 * 4);
  int* cnts    = (int*)alloc(16 * 4);
  ush* h0f     = (ush*)alloc((size_t)N_SEQ * H_DIM * 2);
  ush* h1f     = (ush*)alloc((size_t)N_SEQ * H_DIM * 2);
  ush* h0b     = (ush*)alloc((size_t)N_SEQ * H_DIM * 2);
  ush* h1b     = (ush*)alloc((size_t)N_SEQ * H_DIM * 2);
  float* cf    = (float*)alloc((size_t)N_SEQ * H_DIM * 4);
  float* cb    = (float*)alloc((size_t)N_SEQ * H_DIM * 4);
  float* pooled = (float*)alloc((size_t)B_SAMP * 512 * 4);

  hipMemsetAsync(h0f, 0, (size_t)N_SEQ * H_DIM * 2, stream);
  hipMemsetAsync(h1f, 0, (size_t)N_SEQ * H_DIM * 2, stream);
  hipMemsetAsync(h0b, 0, (size_t)N_SEQ * H_DIM * 2, stream);
  hipMemsetAsync(h1b, 0, (size_t)N_SEQ * H_DIM * 2, stream);

  k_lens<<<NBLK_LENS, 256, 0, stream>>>(tok, lens, blockhist);
  k_offsets<<<1, 64, 0, stream>>>(blockhist, base, cnts);
  k_scatter<<<NBLK_LENS, 256, 0, stream>>>(lens, base, perm, pinv, plens);
  k_tokperm<<<(T_LEN * N_SEQ) / 256, 256, 0, stream>>>(tok, perm, tokperm);
  k_embcvt<<<(V_SIZE * E_DIM) / 256, 256, 0, stream>>>(emb, embbf);
  k_wprep<<<(2 * 1024 * K_DIM) / 256, 256, 0, stream>>>(Wih_f, Whh_f, Wih_b, Whh_b, wptf, wptb);

  dim3 grid(512, 2);
  for (int s = 0; s < T_LEN; ++s) {
    const ush* hrf = (s & 1) ? h1f : h0f;
    ush* hwf       = (s & 1) ? h0f : h1f;
    const ush* hrb = (s & 1) ? h1b : h0b;
    ush* hwb       = (s & 1) ? h0b : h1b;
    k_step<<<grid, 512, 0, stream>>>(embbf, tokperm, plens, cnts, wptf, wptb,
                                     b_f, b_b, hrf, hwf, hrb, hwb, cf, cb, s);
  }
  k_pool<<<B_SAMP, 256, 0, stream>>>(h0f, h1f, h0b, pinv, lens, plen, pooled);
  k_final<<<B_SAMP, 256, 0, stream>>>(pooled, Wlin, blin, out);
}